// Round 3
// baseline (58.250 us; speedup 1.0000x reference)
//
#include <hip/hip_runtime.h>
#include <math.h>

// Problem constants (from reference setup_inputs)
#define CDIM 64
#define CR 16
#define TFR 8
#define NBATCH 16      // NT / T
#define NTOT 128       // NT
#define HWPIX 3136     // 56*56
#define HW4 784        // HWPIX / 4

// clang-native 4-float vector: accepted by __builtin_nontemporal_store
typedef float floatx4 __attribute__((ext_vector_type(4)));

// ---------------------------------------------------------------------------
// Kernel 1: per-(nt, c) spatial mean of x.  grid = NT*C blocks, 256 threads.
// x layout: (NT, C, H, W) contiguous -> block b reduces x[b*3136 .. +3136)
// ---------------------------------------------------------------------------
__global__ __launch_bounds__(256) void spatial_mean_kernel(
    const float* __restrict__ x, float* __restrict__ xbar) {
  const int b = blockIdx.x;  // 0 .. NT*C-1
  const float4* xp = reinterpret_cast<const float4*>(x + (size_t)b * HWPIX);
  float s = 0.f;
  for (int i = threadIdx.x; i < HW4; i += 256) {
    float4 v = xp[i];
    s += (v.x + v.y) + (v.z + v.w);
  }
  // wave (64-lane) butterfly reduce
  #pragma unroll
  for (int off = 32; off > 0; off >>= 1) s += __shfl_down(s, off, 64);
  __shared__ float wsum[4];
  const int lane = threadIdx.x & 63, wid = threadIdx.x >> 6;
  if (lane == 0) wsum[wid] = s;
  __syncthreads();
  if (threadIdx.x == 0) {
    float tot = (wsum[0] + wsum[1]) + (wsum[2] + wsum[3]);
    xbar[b] = tot * (1.0f / (float)HWPIX);
  }
}

// ---------------------------------------------------------------------------
// Kernel 2: fused main pass, one block per (n, c).  grid = N*C = 1024 blocks,
// 256 threads. Prologue computes att[t] (t=0..7) for this (n,c) in shared mem
// from the spatial means (sq_b cancels in the temporal diff; gap[T-1]=0).
// Main loop: each thread walks q = tid, tid+256, ... over the 784 float4s,
// loads all 8 frames, computes
//   S  = x * (1 + att)
//   Sc = shift-conv_T(S)  (k=3, zero pad)
//   Gc = BN(gate-conv_T(x))   [BN folded into conv weights]
//   out = Sc * sigmoid(Gc)
// Stores are non-temporal so `out` doesn't evict x from the LLC.
// ---------------------------------------------------------------------------
__global__ __launch_bounds__(256) void fused_shift_kernel(
    const float* __restrict__ x,
    const float* __restrict__ xbar,
    const float* __restrict__ sq_w,   // (CR, C) row-major
    const float* __restrict__ ex_w,   // (C, CR) row-major
    const float* __restrict__ ex_b,   // (C,)
    const float* __restrict__ shift_w, const float* __restrict__ shift_b,
    const float* __restrict__ gate_w,  const float* __restrict__ gate_b,
    const float* __restrict__ bn_gamma, const float* __restrict__ bn_beta,
    const float* __restrict__ bn_mean,  const float* __restrict__ bn_var,
    float* __restrict__ out) {
  const int n = blockIdx.x >> 6;         // 0..15
  const int c = blockIdx.x & (CDIM - 1); // 0..63
  const int tid = threadIdx.x;

  // ---- att prologue (shared) ----
  __shared__ float dsh[TFR][CDIM];
  __shared__ float gap[TFR][CR];
  __shared__ float attp1_sh[TFR];
  {
    const int base0 = (n * TFR) * CDIM;
    for (int i = tid; i < TFR * CDIM; i += 256) {
      const int t = i >> 6, cc = i & (CDIM - 1);
      dsh[t][cc] = (t == TFR - 1) ? 0.f : (xbar[base0 + cc] - xbar[base0 + t * CDIM + cc]);
    }
  }
  __syncthreads();
  if (tid < TFR * CR) {
    const int t = tid >> 4, k = tid & (CR - 1);
    float g = 0.f;
    #pragma unroll
    for (int cc = 0; cc < CDIM; ++cc) g += sq_w[k * CDIM + cc] * dsh[t][cc];
    gap[t][k] = g;
  }
  __syncthreads();
  if (tid < TFR) {
    float a = ex_b[c];
    #pragma unroll
    for (int k = 0; k < CR; ++k) a += ex_w[c * CR + k] * gap[tid][k];
    attp1_sh[tid] = 1.f + 1.f / (1.f + __expf(-a));
  }
  __syncthreads();

  // per-channel constants (uniform across block -> scalar regs)
  const float sw0 = shift_w[c * 3 + 0], sw1 = shift_w[c * 3 + 1],
              sw2 = shift_w[c * 3 + 2], sb = shift_b[c];
  const float inv = bn_gamma[c] * rsqrtf(bn_var[c] + 1e-3f);
  const float g0 = gate_w[c * 3 + 0] * inv, g1 = gate_w[c * 3 + 1] * inv,
              g2 = gate_w[c * 3 + 2] * inv;
  const float gbias = (gate_b[c] - bn_mean[c]) * inv + bn_beta[c];

  float ap1[TFR];
  #pragma unroll
  for (int t = 0; t < TFR; ++t) ap1[t] = attp1_sh[t];

  const size_t base_nc = ((size_t)(n * TFR) * CDIM + c) * HWPIX;
  const size_t tstride = (size_t)CDIM * HWPIX;  // frame stride in floats
  const float4 zero4 = make_float4(0.f, 0.f, 0.f, 0.f);

  for (int i = tid; i < HW4; i += 256) {
    const size_t off = base_nc + (size_t)i * 4;
    float4 xv[TFR], Sv[TFR];
    #pragma unroll
    for (int t = 0; t < TFR; ++t) {
      xv[t] = *reinterpret_cast<const float4*>(x + off + (size_t)t * tstride);
      Sv[t].x = xv[t].x * ap1[t];
      Sv[t].y = xv[t].y * ap1[t];
      Sv[t].z = xv[t].z * ap1[t];
      Sv[t].w = xv[t].w * ap1[t];
    }
    #pragma unroll
    for (int t = 0; t < TFR; ++t) {
      const float4 Sm = (t > 0) ? Sv[t - 1] : zero4;
      const float4 Sp = (t < TFR - 1) ? Sv[t + 1] : zero4;
      const float4 xm = (t > 0) ? xv[t - 1] : zero4;
      const float4 xp = (t < TFR - 1) ? xv[t + 1] : zero4;
      floatx4 o;
      {
        const float sc = sb + sw0 * Sm.x + sw1 * Sv[t].x + sw2 * Sp.x;
        const float gc = gbias + g0 * xm.x + g1 * xv[t].x + g2 * xp.x;
        o.x = sc * (1.f / (1.f + __expf(-gc)));
      }
      {
        const float sc = sb + sw0 * Sm.y + sw1 * Sv[t].y + sw2 * Sp.y;
        const float gc = gbias + g0 * xm.y + g1 * xv[t].y + g2 * xp.y;
        o.y = sc * (1.f / (1.f + __expf(-gc)));
      }
      {
        const float sc = sb + sw0 * Sm.z + sw1 * Sv[t].z + sw2 * Sp.z;
        const float gc = gbias + g0 * xm.z + g1 * xv[t].z + g2 * xp.z;
        o.z = sc * (1.f / (1.f + __expf(-gc)));
      }
      {
        const float sc = sb + sw0 * Sm.w + sw1 * Sv[t].w + sw2 * Sp.w;
        const float gc = gbias + g0 * xm.w + g1 * xv[t].w + g2 * xp.w;
        o.w = sc * (1.f / (1.f + __expf(-gc)));
      }
      // non-temporal: out is never re-read; keep x resident in LLC instead
      __builtin_nontemporal_store(
          o, reinterpret_cast<floatx4*>(out + off + (size_t)t * tstride));
    }
  }
}

extern "C" void kernel_launch(void* const* d_in, const int* in_sizes, int n_in,
                              void* d_out, int out_size, void* d_ws, size_t ws_size,
                              hipStream_t stream) {
  const float* x        = (const float*)d_in[0];
  const float* shift_w  = (const float*)d_in[1];
  const float* shift_b  = (const float*)d_in[2];
  const float* gate_w   = (const float*)d_in[3];
  const float* gate_b   = (const float*)d_in[4];
  const float* bn_gamma = (const float*)d_in[5];
  const float* bn_beta  = (const float*)d_in[6];
  const float* bn_mean  = (const float*)d_in[7];
  const float* bn_var   = (const float*)d_in[8];
  const float* sq_w     = (const float*)d_in[9];
  // d_in[10] = sq_b  (cancels in temporal diff -> unused)
  const float* ex_w     = (const float*)d_in[11];
  const float* ex_b     = (const float*)d_in[12];
  float* out = (float*)d_out;

  float* xbar = (float*)d_ws;  // NT*C floats

  spatial_mean_kernel<<<NTOT * CDIM, 256, 0, stream>>>(x, xbar);
  fused_shift_kernel<<<NBATCH * CDIM, 256, 0, stream>>>(
      x, xbar, sq_w, ex_w, ex_b, shift_w, shift_b, gate_w, gate_b,
      bn_gamma, bn_beta, bn_mean, bn_var, out);
}